// Round 6
// baseline (273.440 us; speedup 1.0000x reference)
//
#include <hip/hip_runtime.h>
#include <stdint.h>

#define M_ROWS 32768
#define I_DIM 256
#define H_DIM 512
#define C_DIM 1024
#define O_DIM 512

typedef __attribute__((ext_vector_type(8))) short bf16x8;
typedef __attribute__((ext_vector_type(4))) float f32x4;

// ---------------------------------------------------------------------------
// 2-plane RNE split: x = hi + mid + r2, |r2| <= 2^-18 |x|.
// ---------------------------------------------------------------------------
__device__ __forceinline__ ushort bf16_rne(float f) {
    unsigned u = __float_as_uint(f);
    unsigned r = u + 0x7FFFu + ((u >> 16) & 1u);
    return (ushort)(r >> 16);
}
__device__ __forceinline__ float bf16_f32(ushort h) {
    return __uint_as_float(((unsigned)h) << 16);
}
__device__ __forceinline__ void split2(float f, ushort& hi, ushort& mid) {
    hi = bf16_rne(f);
    mid = bf16_rne(f - bf16_f32(hi));
}

__device__ __forceinline__ void async_ld16(const void* g, void* l) {
    __builtin_amdgcn_global_load_lds(
        (const __attribute__((address_space(1))) void*)g,
        (__attribute__((address_space(3))) void*)l, 16, 0, 0);
}

// Monotone packing: larger packed <=> (larger value, then smaller col index)
__device__ __forceinline__ unsigned long long packvi(float v, int col) {
    unsigned u = __float_as_uint(v);
    u = (u & 0x80000000u) ? ~u : (u | 0x80000000u);
    return ((unsigned long long)u << 32) | (unsigned)(~col);
}

// Swizzle: within each 64B k32-group of a row, 16B chunk kc sits at slot
// (kc + (row>>1)) & 3 -> stride-64B fragment ds_read_b128 is conflict-free
// while rows stay DMA-contiguous (verified R5: SQ_LDS_BANK_CONFLICT == 0).
__device__ __forceinline__ int slot_of(int kc, int row) {
    return (kc + ((row >> 1) & 3)) & 3;
}

// ---------------------------------------------------------------------------
// prep: weight splits (permuted layout) + log-softmax table + part[] zero.
//   blocks [0,64)    : W1 split  (512x256)
//   blocks [64,320)  : W2 split  (1024x512)
//   blocks [320,384) : LS table, 16 columns per block (coalesced Wo reads)
//   blocks [384,512) : part[] = 0
// ---------------------------------------------------------------------------
__global__ __launch_bounds__(256)
void prep(const float* __restrict__ W1, ushort* __restrict__ w1h, ushort* __restrict__ w1m,
          const float* __restrict__ W2, ushort* __restrict__ w2h, ushort* __restrict__ w2m,
          const float* __restrict__ Wo, const float* __restrict__ bo,
          float* __restrict__ LS, unsigned long long* __restrict__ part) {
    __shared__ float red[16][17];
    const int b = blockIdx.x;
    const int t = threadIdx.x;
    if (b < 320) {
        const int isW1 = (b < 64);
        const float* W = isW1 ? W1 : W2;
        ushort* hh = isW1 ? w1h : w2h;
        ushort* mm = isW1 ? w1m : w2m;
        const int K = isW1 ? I_DIM : H_DIM;
        const int cpr = K >> 3;                       // 16B chunks per row
        int gid = (isW1 ? b : b - 64) * 256 + t;
        int row = gid / cpr;
        int rem = gid - row * cpr;
        int g = rem >> 2, kc = rem & 3;
        float4 v0 = *(const float4*)(W + (size_t)gid * 8);
        float4 v1 = *(const float4*)(W + (size_t)gid * 8 + 4);
        __align__(16) ushort h[8], m[8];
        float f[8];
        *(float4*)&f[0] = v0; *(float4*)&f[4] = v1;
        #pragma unroll
        for (int j = 0; j < 8; ++j) split2(f[j], h[j], m[j]);
        size_t dst = (size_t)row * K + g * 32 + slot_of(kc, row) * 8;
        *(uint4*)(hh + dst) = *(uint4*)h;
        *(uint4*)(mm + dst) = *(uint4*)m;
    } else if (b < 384) {
        const int j0 = (b - 320) * 16;
        const int c = t & 15, q = t >> 4;
        float v[32];
        float mx = -3.4e38f;
        #pragma unroll
        for (int i = 0; i < 32; ++i) {
            int r = q + 16 * i;
            v[i] = Wo[(size_t)r * C_DIM + j0 + c] + bo[r];
            mx = fmaxf(mx, v[i]);
        }
        red[q][c] = mx;
        __syncthreads();
        #pragma unroll
        for (int s = 8; s > 0; s >>= 1) {
            if (q < s) red[q][c] = fmaxf(red[q][c], red[q + s][c]);
            __syncthreads();
        }
        mx = red[0][c];
        __syncthreads();
        float sum = 0.f;
        #pragma unroll
        for (int i = 0; i < 32; ++i) sum += expf(v[i] - mx);
        red[q][c] = sum;
        __syncthreads();
        #pragma unroll
        for (int s = 8; s > 0; s >>= 1) {
            if (q < s) red[q][c] += red[q + s][c];
            __syncthreads();
        }
        float lse = mx + logf(red[0][c]);
        #pragma unroll
        for (int i = 0; i < 32; ++i)
            LS[(size_t)(j0 + c) * O_DIM + q + 16 * i] = v[i] - lse;
    } else {
        part[(b - 384) * 256 + t] = 0ull;
    }
}

// ---------------------------------------------------------------------------
// GEMM1 (MFMA, 3 products, double-buffered LDS, 1 barrier/iter):
// H = relu(X @ W1^T + b1) -> two bf16 planes (permuted layout), coalesced
// stores via LDS staging. Block 128x128, waves 2x2 of 64x64. K iters = 8.
// ---------------------------------------------------------------------------
__global__ __launch_bounds__(256, 2)
void gemm1_mfma(const float* __restrict__ X, const ushort* __restrict__ W1h,
                const ushort* __restrict__ W1m, const float* __restrict__ b1,
                ushort* __restrict__ Hh, ushort* __restrict__ Hm) {
    __shared__ __align__(16) ushort As[2][2][4096];   // [buf][plane][128*32]
    __shared__ __align__(16) ushort Bs[2][2][4096];

    const int tid = threadIdx.x;
    const int lane = tid & 63, wave = tid >> 6;
    const int wm = wave >> 1, wn = wave & 1;
    const int lcol = lane & 15, quad = lane >> 4;
    const int nBase = blockIdx.x * 128;   // x = n: 4 consecutive blocks share X slab
    const int mBase = blockIdx.y * 128;
    const int s_row = tid >> 1, s_half = tid & 1;
    const int bplane = wave >> 1;
    const ushort* wp = bplane ? W1m : W1h;
    const int brow0 = (wave & 1) * 64;
    const int lrow = lane >> 2, lk = (lane & 3) * 8;

    f32x4 acc[4][4];
    #pragma unroll
    for (int i = 0; i < 4; ++i)
        #pragma unroll
        for (int j = 0; j < 4; ++j)
            acc[i][j] = (f32x4){0.f, 0.f, 0.f, 0.f};

    int aoff[4], boff[4];
    #pragma unroll
    for (int t = 0; t < 4; ++t) {
        int ra = wm * 64 + t * 16 + lcol;
        int rb = wn * 64 + t * 16 + lcol;
        aoff[t] = ra * 32 + slot_of(quad, ra) * 8;
        boff[t] = rb * 32 + slot_of(quad, rb) * 8;
    }
    const int sl0 = slot_of(s_half * 2,     s_row);
    const int sl1 = slot_of(s_half * 2 + 1, s_row);
    const float* xrow = X + (size_t)(mBase + s_row) * I_DIM + s_half * 16;

    float4 xr[2][4];
    // ---- prologue: X(0) -> regs -> A buf0; B DMA buf0; X(1) -> regs ----
    #pragma unroll
    for (int i = 0; i < 4; ++i) xr[0][i] = ((const float4*)xrow)[i];
    {
        float f[16];
        #pragma unroll
        for (int i = 0; i < 4; ++i) *(float4*)&f[i * 4] = xr[0][i];
        bf16x8 h0, h1, m0, m1;
        #pragma unroll
        for (int j = 0; j < 8; ++j) {
            ushort hu, mu;
            split2(f[j], hu, mu);
            h0[j] = (short)hu; m0[j] = (short)mu;
            split2(f[j + 8], hu, mu);
            h1[j] = (short)hu; m1[j] = (short)mu;
        }
        *(bf16x8*)&As[0][0][s_row * 32 + sl0 * 8] = h0;
        *(bf16x8*)&As[0][0][s_row * 32 + sl1 * 8] = h1;
        *(bf16x8*)&As[0][1][s_row * 32 + sl0 * 8] = m0;
        *(bf16x8*)&As[0][1][s_row * 32 + sl1 * 8] = m1;
    }
    #pragma unroll
    for (int i = 0; i < 4; ++i) {
        int r = brow0 + i * 16;
        async_ld16(wp + (size_t)(nBase + r + lrow) * I_DIM + lk, &Bs[0][bplane][r * 32]);
    }
    #pragma unroll
    for (int i = 0; i < 4; ++i) xr[1][i] = ((const float4*)(xrow + 32))[i];

    #pragma unroll 2
    for (int ks = 0; ks < 8; ++ks) {
        const int cur = ks & 1;
        __syncthreads();   // drains DMAs/ds_writes into cur; readers of nxt done
        if (ks < 7) {
            const int k0 = (ks + 1) * 32;
            #pragma unroll
            for (int i = 0; i < 4; ++i) {
                int r = brow0 + i * 16;
                async_ld16(wp + (size_t)(nBase + r + lrow) * I_DIM + k0 + lk,
                           &Bs[cur ^ 1][bplane][r * 32]);
            }
            float f[16];
            #pragma unroll
            for (int i = 0; i < 4; ++i) *(float4*)&f[i * 4] = xr[(ks + 1) & 1][i];
            bf16x8 h0, h1, m0, m1;
            #pragma unroll
            for (int j = 0; j < 8; ++j) {
                ushort hu, mu;
                split2(f[j], hu, mu);
                h0[j] = (short)hu; m0[j] = (short)mu;
                split2(f[j + 8], hu, mu);
                h1[j] = (short)hu; m1[j] = (short)mu;
            }
            *(bf16x8*)&As[cur ^ 1][0][s_row * 32 + sl0 * 8] = h0;
            *(bf16x8*)&As[cur ^ 1][0][s_row * 32 + sl1 * 8] = h1;
            *(bf16x8*)&As[cur ^ 1][1][s_row * 32 + sl0 * 8] = m0;
            *(bf16x8*)&As[cur ^ 1][1][s_row * 32 + sl1 * 8] = m1;
        }
        if (ks < 6) {
            const float* xp = xrow + (ks + 2) * 32;
            #pragma unroll
            for (int i = 0; i < 4; ++i) xr[ks & 1][i] = ((const float4*)xp)[i];
        }

        bf16x8 af[4][2];
        #pragma unroll
        for (int mt = 0; mt < 4; ++mt) {
            af[mt][0] = *(const bf16x8*)&As[cur][0][aoff[mt]];
            af[mt][1] = *(const bf16x8*)&As[cur][1][aoff[mt]];
        }
        #pragma unroll
        for (int nt = 0; nt < 4; ++nt) {
            bf16x8 bh = *(const bf16x8*)&Bs[cur][0][boff[nt]];
            bf16x8 bm = *(const bf16x8*)&Bs[cur][1][boff[nt]];
            #pragma unroll
            for (int mt = 0; mt < 4; ++mt) {
                f32x4 a = acc[mt][nt];
                a = __builtin_amdgcn_mfma_f32_16x16x32_bf16(af[mt][1], bh, a, 0, 0, 0);
                a = __builtin_amdgcn_mfma_f32_16x16x32_bf16(af[mt][0], bm, a, 0, 0, 0);
                a = __builtin_amdgcn_mfma_f32_16x16x32_bf16(af[mt][0], bh, a, 0, 0, 0);
                acc[mt][nt] = a;
            }
        }
    }

    // ---- epilogue: bias+relu+split, staged in LDS (permuted-global layout),
    //      then coalesced uint4 copies. Two passes; acc stays live.
    ushort* LB = &As[0][0][0];   // 16384 ushorts = full As block
    #pragma unroll
    for (int plane = 0; plane < 2; ++plane) {
        __syncthreads();
        #pragma unroll
        for (int nt = 0; nt < 4; ++nt) {
            int colRel = wn * 64 + nt * 16 + lcol;
            int g = colRel >> 5, kc = (colRel >> 3) & 3, pos = colRel & 7;
            float bias = b1[nBase + colRel];
            #pragma unroll
            for (int mt = 0; mt < 4; ++mt) {
                #pragma unroll
                for (int r = 0; r < 4; ++r) {
                    int rowRel = wm * 64 + mt * 16 + quad * 4 + r;
                    float v = fmaxf(acc[mt][nt][r] + bias, 0.f);
                    ushort hu, mu;
                    split2(v, hu, mu);
                    LB[rowRel * 128 + g * 32 + slot_of(kc, rowRel) * 8 + pos]
                        = plane ? mu : hu;
                }
            }
        }
        __syncthreads();
        ushort* dstp = plane ? Hm : Hh;
        #pragma unroll
        for (int l = 0; l < 8; ++l) {
            int c = l * 256 + tid;
            int row = c >> 4, idx = c & 15;
            *(uint4*)(dstp + (size_t)(mBase + row) * H_DIM + nBase + idx * 8)
                = *(const uint4*)&LB[row * 128 + idx * 8];
        }
    }
}

// ---------------------------------------------------------------------------
// GEMM2 (MFMA, 3 products, all-DMA double-buffered staging, 1 barrier/iter)
// + fused argmax via atomicMax. K iters = 16.
// ---------------------------------------------------------------------------
__global__ __launch_bounds__(256, 2)
void gemm2_mfma(const ushort* __restrict__ Hh, const ushort* __restrict__ Hm,
                const ushort* __restrict__ W2h, const ushort* __restrict__ W2m,
                const float* __restrict__ b2,
                unsigned long long* __restrict__ part) {
    __shared__ __align__(16) ushort As[2][2][4096];   // [buf][plane][128*32]
    __shared__ __align__(16) ushort Bs[2][2][4096];
    const int tid = threadIdx.x;
    const int lane = tid & 63, wave = tid >> 6;
    const int wm = wave >> 1, wn = wave & 1;
    const int lcol = lane & 15, quad = lane >> 4;
    const int nBase = blockIdx.x * 128;   // x = n: 8 consecutive blocks share H slab
    const int mBase = blockIdx.y * 128;
    const int lrow = lane >> 2, lk = (lane & 3) * 8;

    // wave -> (global plane, LDS buffer pair) 1:1
    const ushort* gsrc;
    ushort *lb0, *lb1;
    switch (wave) {
        case 0: gsrc = Hh  + (size_t)mBase * H_DIM; lb0 = As[0][0]; lb1 = As[1][0]; break;
        case 1: gsrc = Hm  + (size_t)mBase * H_DIM; lb0 = As[0][1]; lb1 = As[1][1]; break;
        case 2: gsrc = W2h + (size_t)nBase * H_DIM; lb0 = Bs[0][0]; lb1 = Bs[1][0]; break;
        default: gsrc = W2m + (size_t)nBase * H_DIM; lb0 = Bs[0][1]; lb1 = Bs[1][1]; break;
    }

    f32x4 acc[4][4];
    #pragma unroll
    for (int i = 0; i < 4; ++i)
        #pragma unroll
        for (int j = 0; j < 4; ++j)
            acc[i][j] = (f32x4){0.f, 0.f, 0.f, 0.f};

    int aoff[4], boff[4];
    #pragma unroll
    for (int t = 0; t < 4; ++t) {
        int ra = wm * 64 + t * 16 + lcol;
        int rb = wn * 64 + t * 16 + lcol;
        aoff[t] = ra * 32 + slot_of(quad, ra) * 8;
        boff[t] = rb * 32 + slot_of(quad, rb) * 8;
    }

    // prologue: DMA k-step 0 into buf0
    #pragma unroll
    for (int j = 0; j < 8; ++j)
        async_ld16(gsrc + (size_t)(j * 16 + lrow) * H_DIM + lk, lb0 + j * 512);

    #pragma unroll 2
    for (int ks = 0; ks < 16; ++ks) {
        const int cur = ks & 1;
        __syncthreads();   // own DMAs into cur drained (vmcnt0) + readers of nxt done
        if (ks < 15) {
            const int k0 = (ks + 1) * 32;
            ushort* lb = cur ? lb0 : lb1;
            #pragma unroll
            for (int j = 0; j < 8; ++j)
                async_ld16(gsrc + (size_t)(j * 16 + lrow) * H_DIM + k0 + lk,
                           lb + j * 512);
        }

        bf16x8 af[4][2];
        #pragma unroll
        for (int mt = 0; mt < 4; ++mt) {
            af[mt][0] = *(const bf16x8*)&As[cur][0][aoff[mt]];
            af[mt][1] = *(const bf16x8*)&As[cur][1][aoff[mt]];
        }
        #pragma unroll
        for (int nt = 0; nt < 4; ++nt) {
            bf16x8 bh = *(const bf16x8*)&Bs[cur][0][boff[nt]];
            bf16x8 bm = *(const bf16x8*)&Bs[cur][1][boff[nt]];
            #pragma unroll
            for (int mt = 0; mt < 4; ++mt) {
                f32x4 a = acc[mt][nt];
                a = __builtin_amdgcn_mfma_f32_16x16x32_bf16(af[mt][1], bh, a, 0, 0, 0);
                a = __builtin_amdgcn_mfma_f32_16x16x32_bf16(af[mt][0], bm, a, 0, 0, 0);
                a = __builtin_amdgcn_mfma_f32_16x16x32_bf16(af[mt][0], bh, a, 0, 0, 0);
                acc[mt][nt] = a;
            }
        }
    }

    // ---- epilogue: bias + argmax over this 128-col block -> atomicMax ----
    #pragma unroll
    for (int mt = 0; mt < 4; ++mt) {
        #pragma unroll
        for (int r = 0; r < 4; ++r) {
            unsigned long long best = 0ull;
            #pragma unroll
            for (int nt = 0; nt < 4; ++nt) {
                int col = nBase + wn * 64 + nt * 16 + lcol;
                float v = acc[mt][nt][r] + b2[col];
                unsigned long long p = packvi(v, col);
                if (p > best) best = p;
            }
            #pragma unroll
            for (int off = 1; off < 16; off <<= 1) {
                unsigned long long o = __shfl_xor((long long)best, off, 64);
                if (o > best) best = o;
            }
            if (lcol == 0) {
                int row = mBase + wm * 64 + mt * 16 + quad * 4 + r;
                atomicMax(&part[row], best);
            }
        }
    }
}

// out[row,:] = LS[jstar(part[row]), :]; 2 rows per block
__global__ __launch_bounds__(256)
void gather_out(const unsigned long long* __restrict__ part,
                const float* __restrict__ LS, float* __restrict__ out) {
    const int tid = threadIdx.x;
    const int row = blockIdx.x * 2 + (tid >> 7);
    const int q = tid & 127;
    unsigned long long best = part[row];
    unsigned u = (unsigned)(best >> 32);
    float v = (u & 0x80000000u) ? __uint_as_float(u ^ 0x80000000u)
                                : __uint_as_float(~u);
    int col = (int)(~(unsigned)best) & (C_DIM - 1);
    int j = (v > 0.f) ? col : 0;   // all-nonpositive c => relu zeros => top_k picks 0
    float4 val = ((const float4*)LS)[(size_t)j * 128 + q];
    ((float4*)out)[(size_t)row * 128 + q] = val;
}

extern "C" void kernel_launch(void* const* d_in, const int* in_sizes, int n_in,
                              void* d_out, int out_size, void* d_ws, size_t ws_size,
                              hipStream_t stream) {
    const float* x     = (const float*)d_in[0];
    const float* i2m_w = (const float*)d_in[2];
    const float* i2m_b = (const float*)d_in[3];
    const float* m2h_w = (const float*)d_in[4];
    const float* m2h_b = (const float*)d_in[5];
    const float* h2o_w = (const float*)d_in[6];
    const float* h2o_b = (const float*)d_in[7];
    float* out = (float*)d_out;

    // ws layout (bytes):
    //   [0, 256K)        w1 hi plane   [256K, 512K)  w1 mid plane
    //   [512K, 1.5M)     w2 hi plane   [1.5M, 2.5M)  w2 mid plane
    //   [2.5M, 4.5M)     LS table (1024 x 512 fp32)
    //   [4.5M, 4.75M)    part: 32768 u64 (atomicMax targets, zeroed in prep)
    char* ws = (char*)d_ws;
    ushort* w1h = (ushort*)(ws);
    ushort* w1m = (ushort*)(ws + 262144);
    ushort* w2h = (ushort*)(ws + 524288);
    ushort* w2m = (ushort*)(ws + 1572864);
    float*  LS  = (float*)(ws + 2621440);
    unsigned long long* part = (unsigned long long*)(ws + 4718592);

    // H planes live in d_out (2 x 32768*512 ushort = 64MB = exactly out_size*4B)
    ushort* Hh = (ushort*)d_out;
    ushort* Hm = Hh + (size_t)M_ROWS * H_DIM;

    prep<<<512, 256, 0, stream>>>(i2m_w, w1h, w1m, m2h_w, w2h, w2m,
                                  h2o_w, h2o_b, LS, part);
    gemm1_mfma<<<dim3(H_DIM / 128, M_ROWS / 128), 256, 0, stream>>>(
        x, w1h, w1m, i2m_b, Hh, Hm);
    gemm2_mfma<<<dim3(C_DIM / 128, M_ROWS / 128), 256, 0, stream>>>(
        Hh, Hm, w2h, w2m, m2h_b, part);
    gather_out<<<M_ROWS / 2, 256, 0, stream>>>(part, LS, out);
}